// Round 14
// baseline (471.584 us; speedup 1.0000x reference)
//
#include <hip/hip_runtime.h>
#include <hip/hip_cooperative_groups.h>
#include <hip/hip_bf16.h>
#include <math.h>
#include <stdint.h>

namespace cg = cooperative_groups;

// Problem constants
#define NB   2
#define NC   256
#define NSP  4096      // H*W
#define NUSP 1024      // Hu*Wu
#define NHEADS 8
#define HDIM 32
constexpr float SCL  = 0.17677669529663687f;   // 32^-0.5
constexpr float QSCL = 0.17677669529663687f * 1.4426950408889634f;  // SCL*log2(e)

typedef short short8 __attribute__((ext_vector_type(8)));
typedef float f32x4  __attribute__((ext_vector_type(4)));

__device__ __forceinline__ float fexp2(float x) {
#if __has_builtin(__builtin_amdgcn_exp2f)
  return __builtin_amdgcn_exp2f(x);
#else
  return exp2f(x);
#endif
}

// ---------- scratch (device globals referenced ONLY from device code) ----------
__device__ __align__(16) float g_kv    [NB * 512 * NUSP];
__device__ __align__(16) float g_qm    [NB * NHEADS * HDIM];
__device__ __align__(16) float g_vpe   [NB * NC * NSP];
__device__ __align__(16) short g_qbf   [NB * NHEADS * NSP * HDIM];  // pre-scaled SCL*log2e
__device__ __align__(16) short g_kbf   [NB * NHEADS * NUSP * HDIM];
__device__ __align__(16) short g_vbf   [NB * NHEADS * HDIM * NUSP];
__device__ __align__(16) short g_tkKbf [NB * NHEADS * 16 * 32];
__device__ __align__(16) short g_tkVT  [NB * NHEADS * 32 * 32];
__device__ __align__(16) short g_xT    [NB * NSP * 256];
__device__ __align__(16) short g_uT    [NB * NUSP * 256];
__device__ __align__(16) short g_sumT  [NB * NSP * 256];
__device__ __align__(16) short g_wbf   [262144];           // Wq | Wkv | Wproj
__device__ __align__(16) short g_wgbf  [2048];             // Wg [32][64]

__device__ __forceinline__ short f2bf(float f) {
  return (short)((__float_as_uint(f) + 0x8000u) >> 16);
}

// ---------- threefry2x32, key = (0, 42) ----------
__device__ __forceinline__ void threefry2x32_042(uint32_t x0, uint32_t x1,
                                                 uint32_t& r0, uint32_t& r1) {
  const uint32_t ks0 = 0u, ks1 = 42u, ks2 = 0u ^ 42u ^ 0x1BD11BDAu;
  x0 += ks0; x1 += ks1;
#define TFR(R) { x0 += x1; x1 = (x1 << (R)) | (x1 >> (32 - (R))); x1 ^= x0; }
  TFR(13) TFR(15) TFR(26) TFR(6)  x0 += ks1; x1 += ks2 + 1u;
  TFR(17) TFR(29) TFR(16) TFR(24) x0 += ks2; x1 += ks0 + 2u;
  TFR(13) TFR(15) TFR(26) TFR(6)  x0 += ks0; x1 += ks1 + 3u;
  TFR(17) TFR(29) TFR(16) TFR(24) x0 += ks1; x1 += ks2 + 4u;
  TFR(13) TFR(15) TFR(26) TFR(6)  x0 += ks2; x1 += ks0 + 5u;
#undef TFR
  r0 = x0; r1 = x1;
}

__device__ __forceinline__ float gumbel_at(uint32_t i) {
  uint32_t y0, y1;
  threefry2x32_042(0u, i, y0, y1);
  uint32_t bits = y0 ^ y1;
  uint32_t fb = (bits >> 9) | 0x3f800000u;
  float u = __uint_as_float(fb) - 1.0f;
  u = fmaxf(u, 1.17549435e-38f);
  return -logf(-logf(u));
}

// ---------- shared-memory union across phases ----------
union MegaSmem {
  struct { float Ls[32][65]; } pack;
  struct { float Ls[64][65]; } gemm;
  struct {
    float zbuf[1024]; float qml[32]; float rv[256]; int ri[256];
    int chosen[4]; int pos[16]; float xg[16][256]; float wl[64][65];
  } t;
  struct { float src[32][33]; float pl[32][33]; float wk[49]; } v;
  struct { short Ps[8][16][88]; } fl;
};

// ================= phase 0: pack =================
__device__ void ph_pack(MegaSmem* sm, int sec,
                        const float* __restrict__ x, const float* __restrict__ upper,
                        const float* __restrict__ Wq, const float* __restrict__ Wkv,
                        const float* __restrict__ Wproj, const float* __restrict__ Wg) {
  const int tid = threadIdx.x;
  if (sec < 160) {
    const float* src;
    short* dst;
    int b, n0, Nsp;
    if (sec < 128) { b = sec >> 6; n0 = (sec & 63) * 64; Nsp = NSP;
                     src = x + (size_t)b * 256 * NSP;  dst = g_xT + (size_t)b * NSP * 256; }
    else           { int s2 = sec - 128; b = s2 >> 4; n0 = (s2 & 15) * 64; Nsp = NUSP;
                     src = upper + (size_t)b * 256 * NUSP; dst = g_uT + (size_t)b * NUSP * 256; }
    for (int cc = 0; cc < 8; cc++) {
      __syncthreads();
      for (int i = tid; i < 2048; i += 256) {
        int d = i >> 6, nl = i & 63;
        sm->pack.Ls[d][nl] = src[(size_t)(cc * 32 + d) * Nsp + n0 + nl];
      }
      __syncthreads();
      int nl = tid >> 2, dseg = (tid & 3) * 8;
      short8 v;
      #pragma unroll
      for (int j = 0; j < 8; j++) v[j] = f2bf(sm->pack.Ls[dseg + j][nl]);
      *(short8*)&dst[(size_t)(n0 + nl) * 256 + cc * 32 + dseg] = v;
    }
  } else {
    if (sec == 160) {
      for (int i = tid; i < 512; i += 256) g_qm[i] = 0.f;
      #pragma unroll
      for (int j = 0; j < 8; j++) g_wgbf[tid * 8 + j] = f2bf(Wg[tid * 8 + j]);
    }
    int base = (sec - 160) * 8192 + tid * 32;
    const float* s;
    if (base < 65536)       s = Wq + base;
    else if (base < 196608) s = Wkv + (base - 65536);
    else                    s = Wproj + (base - 196608);
    short* d = g_wbf + base;
    #pragma unroll
    for (int j = 0; j < 8; j++) {
      float4 f = *(const float4*)&s[j * 4];
      d[j*4+0] = f2bf(f.x); d[j*4+1] = f2bf(f.y);
      d[j*4+2] = f2bf(f.z); d[j*4+3] = f2bf(f.w);
    }
  }
}

// ---------- MFMA conv1x1 GEMM core ----------
__device__ __forceinline__ void gemm_mfma(const short* __restrict__ Wbf,
                                          const short* __restrict__ ST,
                                          int b, int o0, int n0, int Nsp,
                                          int w, int col, int quad,
                                          f32x4 acc[4]) {
  const short* wrow = Wbf + (size_t)(o0 + w * 16 + col) * 256 + quad * 8;
  const short* srow = ST + ((size_t)b * Nsp + n0 + col) * 256 + quad * 8;
  #pragma unroll
  for (int kc = 0; kc < 8; kc++) {
    short8 af = *(const short8*)&wrow[kc * 32];
    #pragma unroll
    for (int t = 0; t < 4; t++) {
      short8 bf = *(const short8*)&srow[(size_t)(t * 16) * 256 + kc * 32];
      acc[t] = __builtin_amdgcn_mfma_f32_16x16x32_bf16(af, bf, acc[t], 0, 0, 0);
    }
  }
}

// ================= phase 1: q/kv conv GEMMs =================
__device__ void ph_gemm(MegaSmem* sm, int bx,
                        const float* __restrict__ bq, const float* __restrict__ bkv) {
  __syncthreads();   // protect LDS union reuse (strided iterations / prior phase)
  const int tid = threadIdx.x;
  const int lane = tid & 63, w = tid >> 6, col = lane & 15, quad = lane >> 4;
  f32x4 acc[4] = {{0,0,0,0},{0,0,0,0},{0,0,0,0},{0,0,0,0}};

  if (bx < 512) {
    const int b = bx >> 8, o0 = ((bx >> 6) & 3) * 64, n0 = (bx & 63) * 64;
    gemm_mfma(g_wbf, g_xT, b, o0, n0, NSP, w, col, quad, acc);
    float sums[4];
    #pragma unroll
    for (int r = 0; r < 4; r++) {
      int ol = w * 16 + quad * 4 + r;
      float bv = bq[o0 + ol];
      float s = 0.f;
      #pragma unroll
      for (int t = 0; t < 4; t++) {
        float val = acc[t][r] + bv;
        sm->gemm.Ls[ol][t * 16 + col] = val;
        s += val;
      }
      sums[r] = s;
    }
    #pragma unroll
    for (int st = 1; st < 16; st <<= 1)
      #pragma unroll
      for (int r = 0; r < 4; r++) sums[r] += __shfl_xor(sums[r], st, 64);
    if (col == 0) {
      #pragma unroll
      for (int r = 0; r < 4; r++)
        atomicAdd(&g_qm[b * 256 + o0 + w * 16 + quad * 4 + r], sums[r] * (1.0f / 4096.0f));
    }
    __syncthreads();
    int nl = tid >> 2, dseg = (tid & 3) * 8;
    #pragma unroll
    for (int hh = 0; hh < 2; hh++) {
      short8 v;
      #pragma unroll
      for (int j = 0; j < 8; j++) v[j] = f2bf(sm->gemm.Ls[hh * 32 + dseg + j][nl] * QSCL);
      int bh = b * 8 + ((o0 + hh * 32) >> 5);
      *(short8*)&g_qbf[((size_t)bh * NSP + n0 + nl) * 32 + dseg] = v;
    }
  } else {
    const int idx = bx - 512;
    const int b = idx >> 7, o0 = ((idx >> 4) & 7) * 64, n0 = (idx & 15) * 64;
    gemm_mfma(g_wbf + 65536, g_uT, b, o0, n0, NUSP, w, col, quad, acc);
    #pragma unroll
    for (int r = 0; r < 4; r++) {
      int ol = w * 16 + quad * 4 + r;
      float bv = bkv[o0 + ol];
      float* orow = g_kv + ((size_t)b * 512 + o0 + ol) * NUSP + n0;
      #pragma unroll
      for (int t = 0; t < 4; t++) {
        float val = acc[t][r] + bv;
        orow[t * 16 + col] = val;
        sm->gemm.Ls[ol][t * 16 + col] = val;
      }
    }
    __syncthreads();
    const int bh = b * 8 + (o0 >> 6);
    {
      int m = tid >> 2, dseg = (tid & 3) * 8;
      short8 v;
      #pragma unroll
      for (int j = 0; j < 8; j++) v[j] = f2bf(sm->gemm.Ls[dseg + j][m]);
      *(short8*)&g_kbf[((size_t)bh * NUSP + n0 + m) * 32 + dseg] = v;
    }
    {
      int d = tid >> 3, m8 = (tid & 7) * 8;
      short8 v;
      #pragma unroll
      for (int j = 0; j < 8; j++) v[j] = f2bf(sm->gemm.Ls[32 + d][m8 + j]);
      *(short8*)&g_vbf[((size_t)bh * 32 + d) * NUSP + n0 + m8] = v;
    }
  }
}

// ================= phase 2: topk + vpe =================
__device__ void ph_mid(MegaSmem* sm, int u,
                       const float* __restrict__ x, const float* __restrict__ Wkv,
                       const float* __restrict__ bkv, const float* __restrict__ Wpe,
                       const float* __restrict__ bpe) {
  __syncthreads();   // protect LDS union reuse
  const int tid = threadIdx.x;
  if (u < 16) {
    const int bh = u;
    const int b = bh >> 3, h = bh & 7;
    if (tid < 32) sm->t.qml[tid] = g_qm[bh * 32 + tid];
    __syncthreads();
    const float* kbase = g_kv + ((size_t)b * 512 + h * 64) * NUSP;
    float zv[4];
    #pragma unroll
    for (int r = 0; r < 4; r++) {
      int m = r * 256 + tid;
      float dot = 0.f;
      #pragma unroll 8
      for (int d = 0; d < 32; d++) dot += sm->t.qml[d] * kbase[(size_t)d * NUSP + m];
      float z = dot * SCL + gumbel_at((uint32_t)(bh * 1024 + m));
      zv[r] = z; sm->t.zbuf[m] = z;
    }
    __syncthreads();
    float mx = fmaxf(fmaxf(zv[0], zv[1]), fmaxf(zv[2], zv[3]));
    sm->t.rv[tid] = mx; __syncthreads();
    for (int st = 128; st > 0; st >>= 1) {
      if (tid < st) sm->t.rv[tid] = fmaxf(sm->t.rv[tid], sm->t.rv[tid + st]);
      __syncthreads();
    }
    float zmax = sm->t.rv[0]; __syncthreads();
    float sp = 0.f; float ev[4];
    #pragma unroll
    for (int r = 0; r < 4; r++) { ev[r] = __expf(zv[r] - zmax); sp += ev[r]; }
    sm->t.rv[tid] = sp; __syncthreads();
    for (int st = 128; st > 0; st >>= 1) {
      if (tid < st) sm->t.rv[tid] += sm->t.rv[tid + st];
      __syncthreads();
    }
    float ssum = sm->t.rv[0]; __syncthreads();
    #pragma unroll
    for (int r = 0; r < 4; r++) sm->t.zbuf[r * 256 + tid] = ev[r] / ssum;
    __syncthreads();
    for (int t = 0; t < 4; t++) {
      float bv = -2.0f; int bi = 0;
      #pragma unroll
      for (int r = 0; r < 4; r++) {
        int m = r * 256 + tid;
        float v = sm->t.zbuf[m];
        if (v > bv) { bv = v; bi = m; }
      }
      sm->t.rv[tid] = bv; sm->t.ri[tid] = bi; __syncthreads();
      for (int st = 128; st > 0; st >>= 1) {
        if (tid < st) {
          float v2 = sm->t.rv[tid + st]; int i2 = sm->t.ri[tid + st];
          if (v2 > sm->t.rv[tid] || (v2 == sm->t.rv[tid] && i2 < sm->t.ri[tid])) {
            sm->t.rv[tid] = v2; sm->t.ri[tid] = i2;
          }
        }
        __syncthreads();
      }
      if (tid == 0) { sm->t.chosen[t] = sm->t.ri[0]; sm->t.zbuf[sm->t.ri[0]] = -2.0f; }
      __syncthreads();
    }
    if (tid < 16) {
      int t = tid & 3, g2 = tid >> 2;
      int dh = g2 >> 1, dw = g2 & 1;
      int m = sm->t.chosen[t];
      int hi = (m >> 5) * 2 + dh, wi = (m & 31) * 2 + dw;
      sm->t.pos[g2 * 4 + t] = hi * 64 + wi;
    }
    __syncthreads();
    for (int i = tid; i < 16 * 256; i += 256) {
      int j = i >> 8, c = i & 255;
      sm->t.xg[j][c] = x[((size_t)b * 256 + c) * NSP + sm->t.pos[j]];
    }
    const int dd = tid & 63, jg = tid >> 6;
    const float bia = bkv[h * 64 + dd];
    float a4[4] = {bia, bia, bia, bia};
    for (int cc2 = 0; cc2 < 4; cc2++) {
      __syncthreads();
      for (int i = tid; i < 4096; i += 256) {
        int r = i >> 6, c = i & 63;
        sm->t.wl[r][c] = Wkv[(size_t)(h * 64 + r) * 256 + cc2 * 64 + c];
      }
      __syncthreads();
      #pragma unroll
      for (int jj = 0; jj < 4; jj++) {
        int j = jg * 4 + jj;
        float a = 0.f;
        #pragma unroll 8
        for (int c = 0; c < 64; c++) a += sm->t.xg[j][cc2 * 64 + c] * sm->t.wl[dd][c];
        a4[jj] += a;
      }
    }
    #pragma unroll
    for (int jj = 0; jj < 4; jj++) {
      int j = jg * 4 + jj;
      if (dd < 32) {
        g_tkKbf[((size_t)bh * 16 + j) * 32 + dd] = f2bf(a4[jj]);
      } else {
        int d = dd - 32;
        g_tkVT[((size_t)bh * 32 + d) * 32 + j] = f2bf(a4[jj]);
        g_tkVT[((size_t)bh * 32 + d) * 32 + 16 + j] = 0;
      }
    }
  } else {
    const int idx = u - 16;
    const int c = idx & 255, b = idx >> 8;
    const int h = c >> 5, d = c & 31;
    const float* vrow = g_kv + ((size_t)b * 512 + h * 64 + 32 + d) * NUSP;
    for (int i = tid; i < 1024; i += 256) sm->v.src[i >> 5][i & 31] = vrow[i];
    if (tid < 49) sm->v.wk[tid] = Wpe[c * 49 + tid];
    __syncthreads();
    const float bia = bpe[c];
    for (int i = tid; i < 1024; i += 256) {
      int hu = i >> 5, wu = i & 31;
      float s = bia;
      #pragma unroll
      for (int kh = 0; kh < 7; kh++) {
        int ih = hu + kh - 3;
        if (ih < 0 || ih > 31) continue;
        #pragma unroll
        for (int kw = 0; kw < 7; kw++) {
          int iw = wu + kw - 3;
          if (iw < 0 || iw > 31) continue;
          s += sm->v.src[ih][iw] * sm->v.wk[kh * 7 + kw];
        }
      }
      sm->v.pl[hu][wu] = s;
    }
    __syncthreads();
    float* orow = g_vpe + ((size_t)b * 256 + c) * NSP;
    for (int i = tid; i < 4096; i += 256) {
      int hh = i >> 6, ww = i & 63;
      int ih = hh >> 1, iw = ww >> 1;
      int ih2 = (hh & 1) ? min(ih + 1, 31) : max(ih - 1, 0);
      int iw2 = (ww & 1) ? min(iw + 1, 31) : max(iw - 1, 0);
      float a  = 0.75f * sm->v.pl[ih][iw]  + 0.25f * sm->v.pl[ih][iw2];
      float bb = 0.75f * sm->v.pl[ih2][iw] + 0.25f * sm->v.pl[ih2][iw2];
      orow[i] = 0.75f * a + 0.25f * bb;
    }
  }
}

// ================= phase 3: flash (v8: 2 q-tiles/wave) =================
__device__ void ph_flash(MegaSmem* sm, int u, const float* __restrict__ bg) {
  __syncthreads();   // protect LDS union reuse
  const int bh = u >> 5;
  const int b = bh >> 3, h = bh & 7;
  const int bxx = u & 31;
  const int tid = threadIdx.x;
  const int lane = tid & 63;
  const int w = tid >> 6;
  const int col = lane & 15;
  const int quad = lane >> 4;
  const int n0 = bxx * 128 + w * 32;

  short* PsA = &sm->fl.Ps[w * 2][0][0];
  short* PsB = &sm->fl.Ps[w * 2 + 1][0][0];

  const short* kb = g_kbf + (size_t)bh * NUSP * 32;
  const short* vb = g_vbf + (size_t)bh * 32 * NUSP;

  short8 qfA = *(const short8*)&g_qbf[((size_t)bh * NSP + n0 + col) * 32 + quad * 8];
  short8 qfB = *(const short8*)&g_qbf[((size_t)bh * NSP + n0 + 16 + col) * 32 + quad * 8];

  f32x4 oA0 = {0,0,0,0}, oA1 = {0,0,0,0}, oB0 = {0,0,0,0}, oB1 = {0,0,0,0};
  float lA[4] = {0,0,0,0}, lB[4] = {0,0,0,0};

  for (int kt = 0; kt < 16; kt++) {
    short8 kf[4];
    #pragma unroll
    for (int t = 0; t < 4; t++)
      kf[t] = *(const short8*)&kb[((size_t)(kt * 64 + t * 16 + col)) * 32 + quad * 8];
    f32x4 sA[4], sB[4];
    #pragma unroll
    for (int t = 0; t < 4; t++) {
      f32x4 z = {0,0,0,0};
      sA[t] = __builtin_amdgcn_mfma_f32_16x16x32_bf16(qfA, kf[t], z, 0, 0, 0);
      sB[t] = __builtin_amdgcn_mfma_f32_16x16x32_bf16(qfB, kf[t], z, 0, 0, 0);
    }
    #pragma unroll
    for (int t = 0; t < 4; t++)
      #pragma unroll
      for (int r = 0; r < 4; r++) {
        float pA = fexp2(sA[t][r]);
        float pB = fexp2(sB[t][r]);
        sA[t][r] = pA; lA[r] += pA;
        sB[t][r] = pB; lB[r] += pB;
      }
    #pragma unroll
    for (int t = 0; t < 4; t++)
      #pragma unroll
      for (int r = 0; r < 4; r++) {
        PsA[(quad * 4 + r) * 88 + t * 16 + col] = f2bf(sA[t][r]);
        PsB[(quad * 4 + r) * 88 + t * 16 + col] = f2bf(sB[t][r]);
      }
    short8 vf0 = *(const short8*)&vb[(size_t)col * NUSP + kt * 64 + quad * 8];
    short8 vf1 = *(const short8*)&vb[(size_t)(col + 16) * NUSP + kt * 64 + quad * 8];
    short8 vf2 = *(const short8*)&vb[(size_t)col * NUSP + kt * 64 + 32 + quad * 8];
    short8 vf3 = *(const short8*)&vb[(size_t)(col + 16) * NUSP + kt * 64 + 32 + quad * 8];
    short8 pA0 = *(const short8*)&PsA[col * 88 + quad * 8];
    short8 pA1 = *(const short8*)&PsA[col * 88 + 32 + quad * 8];
    short8 pB0 = *(const short8*)&PsB[col * 88 + quad * 8];
    short8 pB1 = *(const short8*)&PsB[col * 88 + 32 + quad * 8];
    oA0 = __builtin_amdgcn_mfma_f32_16x16x32_bf16(pA0, vf0, oA0, 0, 0, 0);
    oB0 = __builtin_amdgcn_mfma_f32_16x16x32_bf16(pB0, vf0, oB0, 0, 0, 0);
    oA1 = __builtin_amdgcn_mfma_f32_16x16x32_bf16(pA0, vf1, oA1, 0, 0, 0);
    oB1 = __builtin_amdgcn_mfma_f32_16x16x32_bf16(pB0, vf1, oB1, 0, 0, 0);
    oA0 = __builtin_amdgcn_mfma_f32_16x16x32_bf16(pA1, vf2, oA0, 0, 0, 0);
    oB0 = __builtin_amdgcn_mfma_f32_16x16x32_bf16(pB1, vf2, oB0, 0, 0, 0);
    oA1 = __builtin_amdgcn_mfma_f32_16x16x32_bf16(pA1, vf3, oA1, 0, 0, 0);
    oB1 = __builtin_amdgcn_mfma_f32_16x16x32_bf16(pB1, vf3, oB1, 0, 0, 0);
  }
  #pragma unroll
  for (int st = 1; st < 16; st <<= 1)
    #pragma unroll
    for (int r = 0; r < 4; r++) {
      lA[r] += __shfl_xor(lA[r], st, 64);
      lB[r] += __shfl_xor(lB[r], st, 64);
    }

  const float bg0 = bg[col], bg1 = bg[col + 16];
  short8 kff = *(const short8*)&g_tkKbf[(size_t)bh * 512 + col * 32 + quad * 8];
  short8 vt0 = *(const short8*)&g_tkVT[(size_t)bh * 1024 + col * 32 + quad * 8];
  short8 vt1 = *(const short8*)&g_tkVT[(size_t)bh * 1024 + (col + 16) * 32 + quad * 8];
  short8 b1a = *(const short8*)&g_wgbf[col * 64 + quad * 8];
  short8 b1b = *(const short8*)&g_wgbf[col * 64 + 32 + quad * 8];
  short8 b2a = *(const short8*)&g_wgbf[(col + 16) * 64 + quad * 8];
  short8 b2b = *(const short8*)&g_wgbf[(col + 16) * 64 + 32 + quad * 8];

  #pragma unroll
  for (int tt = 0; tt < 2; tt++) {
    const int nt = n0 + tt * 16;
    short8 qf = tt ? qfB : qfA;
    f32x4 o0 = tt ? oB0 : oA0;
    f32x4 o1 = tt ? oB1 : oA1;
    float* lr = tt ? lB : lA;
    short* myPs = tt ? PsB : PsA;
    f32x4 zf = {0,0,0,0};
    f32x4 co0, co1;
    #pragma unroll
    for (int r = 0; r < 4; r++) {
      float inv = 1.0f / lr[r];
      co0[r] = o0[r] * inv;
      co1[r] = o1[r] * inv;
    }
    f32x4 sf = __builtin_amdgcn_mfma_f32_16x16x32_bf16(qf, kff, zf, 0, 0, 0);
    float flr[4];
    #pragma unroll
    for (int r = 0; r < 4; r++) { float p = fexp2(sf[r]); sf[r] = p; flr[r] = p; }
    #pragma unroll
    for (int st = 1; st < 16; st <<= 1)
      #pragma unroll
      for (int r = 0; r < 4; r++) flr[r] += __shfl_xor(flr[r], st, 64);
    #pragma unroll
    for (int r = 0; r < 4; r++)
      myPs[(quad * 4 + r) * 88 + col] = f2bf(sf[r]);
    short8 pff = {0, 0, 0, 0, 0, 0, 0, 0};
    if (quad < 2) pff = *(const short8*)&myPs[col * 88 + quad * 8];
    f32x4 rf0 = __builtin_amdgcn_mfma_f32_16x16x32_bf16(pff, vt0, zf, 0, 0, 0);
    f32x4 rf1 = __builtin_amdgcn_mfma_f32_16x16x32_bf16(pff, vt1, zf, 0, 0, 0);
    #pragma unroll
    for (int r = 0; r < 4; r++) {
      float inv = 1.0f / flr[r];
      rf0[r] *= inv; rf1[r] *= inv;
    }
    #pragma unroll
    for (int r = 0; r < 4; r++) {
      int q = quad * 4 + r;
      myPs[q * 88 + col]      = f2bf(co0[r]);
      myPs[q * 88 + col + 16] = f2bf(co1[r]);
      myPs[q * 88 + col + 32] = f2bf(rf0[r]);
      myPs[q * 88 + col + 48] = f2bf(rf1[r]);
    }
    short8 a1 = *(const short8*)&myPs[col * 88 + quad * 8];
    short8 a2 = *(const short8*)&myPs[col * 88 + 32 + quad * 8];
    f32x4 G0 = __builtin_amdgcn_mfma_f32_16x16x32_bf16(a1, b1a, zf, 0, 0, 0);
    G0 = __builtin_amdgcn_mfma_f32_16x16x32_bf16(a2, b1b, G0, 0, 0, 0);
    f32x4 G1 = __builtin_amdgcn_mfma_f32_16x16x32_bf16(a1, b2a, zf, 0, 0, 0);
    G1 = __builtin_amdgcn_mfma_f32_16x16x32_bf16(a2, b2b, G1, 0, 0, 0);
    const float* vpe0 = g_vpe + ((size_t)(b * 256 + h * 32 + col)) * NSP + nt;
    const float* vpe1 = g_vpe + ((size_t)(b * 256 + h * 32 + col + 16)) * NSP + nt;
    short* dstb = g_sumT + ((size_t)b * NSP + nt) * 256 + h * 32;
    #pragma unroll
    for (int r = 0; r < 4; r++) {
      int q = quad * 4 + r;
      float g0 = 1.0f / (1.0f + __expf(-(G0[r] + bg0)));
      float g1 = 1.0f / (1.0f + __expf(-(G1[r] + bg1)));
      float out0 = g0 * rf0[r] + (1.0f - g0) * co0[r] + vpe0[q];
      float out1 = g1 * rf1[r] + (1.0f - g1) * co1[r] + vpe1[q];
      dstb[(size_t)q * 256 + col]      = f2bf(out0);
      dstb[(size_t)q * 256 + col + 16] = f2bf(out1);
    }
  }
}

// ================= phase 4: final projection =================
__device__ void ph_proj(int u, const float* __restrict__ bias, float* __restrict__ out) {
  const int b = u >> 8;
  const int o0 = ((u >> 6) & 3) * 64;
  const int n0 = (u & 63) * 64;
  const int tid = threadIdx.x;
  const int lane = tid & 63, w = tid >> 6, col = lane & 15, quad = lane >> 4;
  f32x4 acc[4] = {{0,0,0,0},{0,0,0,0},{0,0,0,0},{0,0,0,0}};
  gemm_mfma(g_wbf + 196608, g_sumT, b, o0, n0, NSP, w, col, quad, acc);
  #pragma unroll
  for (int r = 0; r < 4; r++) {
    int o = o0 + w * 16 + quad * 4 + r;
    float bv = bias[o];
    float* orow = out + ((size_t)b * 256 + o) * NSP + n0;
    #pragma unroll
    for (int t = 0; t < 4; t++)
      orow[t * 16 + col] = acc[t][r] + bv;
  }
}

// ================= the mega kernel =================
__global__ __launch_bounds__(256, 2) void k_all(const float* __restrict__ x,
                                                const float* __restrict__ upper,
                                                const float* __restrict__ Wq,
                                                const float* __restrict__ bq,
                                                const float* __restrict__ Wkv,
                                                const float* __restrict__ bkv,
                                                const float* __restrict__ Wproj,
                                                const float* __restrict__ bproj,
                                                const float* __restrict__ Wpe,
                                                const float* __restrict__ bpe,
                                                const float* __restrict__ Wg,
                                                const float* __restrict__ bg,
                                                float* __restrict__ out) {
  __shared__ MegaSmem sm;
  cg::grid_group grid = cg::this_grid();
  const int bx = blockIdx.x;

  if (bx < 192) ph_pack(&sm, bx, x, upper, Wq, Wkv, Wproj, Wg);
  grid.sync();
  for (int u = bx; u < 768; u += 512) ph_gemm(&sm, u, bq, bkv);
  grid.sync();
  for (int u = bx; u < 528; u += 512) ph_mid(&sm, u, x, Wkv, bkv, Wpe, bpe);
  grid.sync();
  ph_flash(&sm, bx, bg);
  grid.sync();
  ph_proj(bx, bproj, out);
}

extern "C" void kernel_launch(void* const* d_in, const int* in_sizes, int n_in,
                              void* d_out, int out_size, void* d_ws, size_t ws_size,
                              hipStream_t stream) {
  const float* x     = (const float*)d_in[0];
  const float* upper = (const float*)d_in[1];
  const float* Wq    = (const float*)d_in[2];
  const float* bq    = (const float*)d_in[3];
  const float* Wkv   = (const float*)d_in[4];
  const float* bkv   = (const float*)d_in[5];
  const float* Wproj = (const float*)d_in[6];
  const float* bproj = (const float*)d_in[7];
  const float* Wpe   = (const float*)d_in[8];
  const float* bpe   = (const float*)d_in[9];
  const float* Wg    = (const float*)d_in[10];
  const float* bg    = (const float*)d_in[11];
  float* out = (float*)d_out;
  (void)d_ws; (void)ws_size; (void)in_sizes; (void)n_in; (void)out_size;

  void* kargs[] = {
    (void*)&x, (void*)&upper, (void*)&Wq, (void*)&bq, (void*)&Wkv, (void*)&bkv,
    (void*)&Wproj, (void*)&bproj, (void*)&Wpe, (void*)&bpe, (void*)&Wg, (void*)&bg,
    (void*)&out
  };
  hipLaunchCooperativeKernel((const void*)k_all, dim3(512), dim3(256), kargs, 0, stream);
}

// Round 15
// 207.509 us; speedup vs baseline: 2.2726x; 2.2726x over previous
//
#include <hip/hip_runtime.h>
#include <hip/hip_bf16.h>
#include <math.h>
#include <stdint.h>

// Problem constants
#define NB   2
#define NC   256
#define NSP  4096      // H*W
#define NUSP 1024      // Hu*Wu
#define NHEADS 8
#define HDIM 32
constexpr float SCL  = 0.17677669529663687f;   // 32^-0.5
constexpr float QSCL = 0.17677669529663687f * 1.4426950408889634f;  // SCL*log2(e)

typedef short short8 __attribute__((ext_vector_type(8)));
typedef float f32x4  __attribute__((ext_vector_type(4)));

__device__ __forceinline__ float fexp2(float x) {
#if __has_builtin(__builtin_amdgcn_exp2f)
  return __builtin_amdgcn_exp2f(x);
#else
  return exp2f(x);
#endif
}

// ---------- scratch (device globals referenced ONLY from device code) ----------
__device__ __align__(16) float g_kv    [NB * 512 * NUSP];  // conv-kv f32 [b][o=512][m]
__device__ __align__(16) float g_qm    [NB * NHEADS * HDIM];
__device__ __align__(16) float g_vpe   [NB * NC * NSP];    // [b][c][n]
// bf16 MFMA layouts
__device__ __align__(16) short g_qbf   [NB * NHEADS * NSP * HDIM];  // [bh][n][d] (pre-scaled SCL*log2e)
__device__ __align__(16) short g_kbf   [NB * NHEADS * NUSP * HDIM]; // [bh][m][d]
__device__ __align__(16) short g_vbf   [NB * NHEADS * HDIM * NUSP]; // [bh][d][m]
__device__ __align__(16) short g_tkKbf [NB * NHEADS * 16 * 32];     // [bh][key][d]
__device__ __align__(16) short g_tkVT  [NB * NHEADS * 32 * 32];     // [bh][d][keypad32]
__device__ __align__(16) short g_xT    [NB * NSP * 256];   // x^T   [b][n][c]
__device__ __align__(16) short g_uT    [NB * NUSP * 256];  // upper^T [b][m][c]
__device__ __align__(16) short g_sumT  [NB * NSP * 256];   // (attn+vpe)^T [b][n][c]
__device__ __align__(16) short g_wbf   [262144];           // Wq | Wkv | Wproj
__device__ __align__(16) short g_wgbf  [2048];             // Wg [32][64]

// f32 -> bf16 round-half-up
__device__ __forceinline__ short f2bf(float f) {
  return (short)((__float_as_uint(f) + 0x8000u) >> 16);
}

// ---------- threefry2x32, key = (0, 42) ----------
__device__ __forceinline__ void threefry2x32_042(uint32_t x0, uint32_t x1,
                                                 uint32_t& r0, uint32_t& r1) {
  const uint32_t ks0 = 0u, ks1 = 42u, ks2 = 0u ^ 42u ^ 0x1BD11BDAu;
  x0 += ks0; x1 += ks1;
#define TFR(R) { x0 += x1; x1 = (x1 << (R)) | (x1 >> (32 - (R))); x1 ^= x0; }
  TFR(13) TFR(15) TFR(26) TFR(6)  x0 += ks1; x1 += ks2 + 1u;
  TFR(17) TFR(29) TFR(16) TFR(24) x0 += ks2; x1 += ks0 + 2u;
  TFR(13) TFR(15) TFR(26) TFR(6)  x0 += ks0; x1 += ks1 + 3u;
  TFR(17) TFR(29) TFR(16) TFR(24) x0 += ks1; x1 += ks2 + 4u;
  TFR(13) TFR(15) TFR(26) TFR(6)  x0 += ks2; x1 += ks0 + 5u;
#undef TFR
  r0 = x0; r1 = x1;
}

// gumbel, jax_threefry_partitionable path (verified round 5)
__device__ __forceinline__ float gumbel_at(uint32_t i) {
  uint32_t y0, y1;
  threefry2x32_042(0u, i, y0, y1);
  uint32_t bits = y0 ^ y1;
  uint32_t fb = (bits >> 9) | 0x3f800000u;
  float u = __uint_as_float(fb) - 1.0f;
  u = fmaxf(u, 1.17549435e-38f);
  return -logf(-logf(u));
}

// ---------- k_pack_in: x^T, upper^T + W casts + Wg cast + g_qm zero ----------
__global__ __launch_bounds__(256) void k_pack_in(const float* __restrict__ x,
                                                 const float* __restrict__ upper,
                                                 const float* __restrict__ Wq,
                                                 const float* __restrict__ Wkv,
                                                 const float* __restrict__ Wproj,
                                                 const float* __restrict__ Wg) {
  const int sec = blockIdx.x;
  const int tid = threadIdx.x;
  if (sec < 160) {
    __shared__ float Ls[32][65];
    const float* src;
    short* dst;
    int b, n0, Nsp;
    if (sec < 128) { b = sec >> 6; n0 = (sec & 63) * 64; Nsp = NSP;
                     src = x + (size_t)b * 256 * NSP;  dst = g_xT + (size_t)b * NSP * 256; }
    else           { int s2 = sec - 128; b = s2 >> 4; n0 = (s2 & 15) * 64; Nsp = NUSP;
                     src = upper + (size_t)b * 256 * NUSP; dst = g_uT + (size_t)b * NUSP * 256; }
    for (int cc = 0; cc < 8; cc++) {
      __syncthreads();
      for (int i = tid; i < 2048; i += 256) {
        int d = i >> 6, nl = i & 63;
        Ls[d][nl] = src[(size_t)(cc * 32 + d) * Nsp + n0 + nl];
      }
      __syncthreads();
      int nl = tid >> 2, dseg = (tid & 3) * 8;
      short8 v;
      #pragma unroll
      for (int j = 0; j < 8; j++) v[j] = f2bf(Ls[dseg + j][nl]);
      *(short8*)&dst[(size_t)(n0 + nl) * 256 + cc * 32 + dseg] = v;
    }
  } else {
    if (sec == 160) {
      for (int i = tid; i < 512; i += 256) g_qm[i] = 0.f;
      #pragma unroll
      for (int j = 0; j < 8; j++) g_wgbf[tid * 8 + j] = f2bf(Wg[tid * 8 + j]);
    }
    int base = (sec - 160) * 8192 + tid * 32;
    const float* s;
    if (base < 65536)       s = Wq + base;
    else if (base < 196608) s = Wkv + (base - 65536);
    else                    s = Wproj + (base - 196608);
    short* d = g_wbf + base;
    #pragma unroll
    for (int j = 0; j < 8; j++) {
      float4 f = *(const float4*)&s[j * 4];
      d[j*4+0] = f2bf(f.x); d[j*4+1] = f2bf(f.y);
      d[j*4+2] = f2bf(f.z); d[j*4+3] = f2bf(f.w);
    }
  }
}

// ---------- MFMA conv1x1 GEMM core ----------
__device__ __forceinline__ void gemm_mfma(const short* __restrict__ Wbf,
                                          const short* __restrict__ ST,
                                          int b, int o0, int n0, int Nsp,
                                          int w, int col, int quad,
                                          f32x4 acc[4]) {
  const short* wrow = Wbf + (size_t)(o0 + w * 16 + col) * 256 + quad * 8;
  const short* srow = ST + ((size_t)b * Nsp + n0 + col) * 256 + quad * 8;
  #pragma unroll
  for (int kc = 0; kc < 8; kc++) {
    short8 af = *(const short8*)&wrow[kc * 32];
    #pragma unroll
    for (int t = 0; t < 4; t++) {
      short8 bf = *(const short8*)&srow[(size_t)(t * 16) * 256 + kc * 32];
      acc[t] = __builtin_amdgcn_mfma_f32_16x16x32_bf16(af, bf, acc[t], 0, 0, 0);
    }
  }
}

// ---------- k_gemms: q conv (blocks 0..511) + kv conv (512..767), merged ----------
__global__ __launch_bounds__(256) void k_gemms(const float* __restrict__ bq,
                                               const float* __restrict__ bkv) {
  __shared__ float Ls[64][65];
  const int bx = blockIdx.x;
  const int tid = threadIdx.x;
  const int lane = tid & 63, w = tid >> 6, col = lane & 15, quad = lane >> 4;
  f32x4 acc[4] = {{0,0,0,0},{0,0,0,0},{0,0,0,0},{0,0,0,0}};

  if (bx < 512) {
    const int b = bx >> 8, o0 = ((bx >> 6) & 3) * 64, n0 = (bx & 63) * 64;
    gemm_mfma(g_wbf, g_xT, b, o0, n0, NSP, w, col, quad, acc);
    float sums[4];
    #pragma unroll
    for (int r = 0; r < 4; r++) {
      int ol = w * 16 + quad * 4 + r;
      float bv = bq[o0 + ol];
      float s = 0.f;
      #pragma unroll
      for (int t = 0; t < 4; t++) {
        float val = acc[t][r] + bv;
        Ls[ol][t * 16 + col] = val;
        s += val;
      }
      sums[r] = s;
    }
    #pragma unroll
    for (int st = 1; st < 16; st <<= 1)
      #pragma unroll
      for (int r = 0; r < 4; r++) sums[r] += __shfl_xor(sums[r], st, 64);
    if (col == 0) {
      #pragma unroll
      for (int r = 0; r < 4; r++)
        atomicAdd(&g_qm[b * 256 + o0 + w * 16 + quad * 4 + r], sums[r] * (1.0f / 4096.0f));
    }
    __syncthreads();
    int nl = tid >> 2, dseg = (tid & 3) * 8;
    #pragma unroll
    for (int hh = 0; hh < 2; hh++) {
      short8 v;
      #pragma unroll
      for (int j = 0; j < 8; j++) v[j] = f2bf(Ls[hh * 32 + dseg + j][nl] * QSCL);
      int bh = b * 8 + ((o0 + hh * 32) >> 5);
      *(short8*)&g_qbf[((size_t)bh * NSP + n0 + nl) * 32 + dseg] = v;
    }
  } else {
    const int idx = bx - 512;
    const int b = idx >> 7, o0 = ((idx >> 4) & 7) * 64, n0 = (idx & 15) * 64;
    gemm_mfma(g_wbf + 65536, g_uT, b, o0, n0, NUSP, w, col, quad, acc);
    #pragma unroll
    for (int r = 0; r < 4; r++) {
      int ol = w * 16 + quad * 4 + r;
      float bv = bkv[o0 + ol];
      float* orow = g_kv + ((size_t)b * 512 + o0 + ol) * NUSP + n0;
      #pragma unroll
      for (int t = 0; t < 4; t++) {
        float val = acc[t][r] + bv;
        orow[t * 16 + col] = val;
        Ls[ol][t * 16 + col] = val;
      }
    }
    __syncthreads();
    const int bh = b * 8 + (o0 >> 6);
    {  // k rows [0,32) -> kbf transpose
      int m = tid >> 2, dseg = (tid & 3) * 8;
      short8 v;
      #pragma unroll
      for (int j = 0; j < 8; j++) v[j] = f2bf(Ls[dseg + j][m]);
      *(short8*)&g_kbf[((size_t)bh * NUSP + n0 + m) * 32 + dseg] = v;
    }
    {  // v rows [32,64) -> vbf straight
      int d = tid >> 3, m8 = (tid & 7) * 8;
      short8 v;
      #pragma unroll
      for (int j = 0; j < 8; j++) v[j] = f2bf(Ls[32 + d][m8 + j]);
      *(short8*)&g_vbf[((size_t)bh * 32 + d) * NUSP + n0 + m8] = v;
    }
  }
}

// ---------- k_mid: topk (blocks 0..15) + vpe (16..527), merged ----------
union MidSmem {
  struct {
    float zbuf[1024]; float qml[32]; float rv[256]; int ri[256];
    int chosen[4]; int pos[16]; float xg[16][256]; float wl[64][65];
  } t;
  struct {
    float src[32][33]; float pl[32][33]; float wk[49];
  } v;
};

__global__ __launch_bounds__(256) void k_mid(const float* __restrict__ x,
                                             const float* __restrict__ Wkv,
                                             const float* __restrict__ bkv,
                                             const float* __restrict__ Wpe,
                                             const float* __restrict__ bpe) {
  __shared__ MidSmem sm;
  const int tid = threadIdx.x;
  if (blockIdx.x < 16) {
    // ================= topk =================
    const int bh = blockIdx.x;
    const int b = bh >> 3, h = bh & 7;
    if (tid < 32) sm.t.qml[tid] = g_qm[bh * 32 + tid];
    __syncthreads();
    const float* kbase = g_kv + ((size_t)b * 512 + h * 64) * NUSP;
    float zv[4];
    #pragma unroll
    for (int r = 0; r < 4; r++) {
      int m = r * 256 + tid;
      float dot = 0.f;
      #pragma unroll 8
      for (int d = 0; d < 32; d++) dot += sm.t.qml[d] * kbase[(size_t)d * NUSP + m];
      float z = dot * SCL + gumbel_at((uint32_t)(bh * 1024 + m));
      zv[r] = z; sm.t.zbuf[m] = z;
    }
    __syncthreads();
    float mx = fmaxf(fmaxf(zv[0], zv[1]), fmaxf(zv[2], zv[3]));
    sm.t.rv[tid] = mx; __syncthreads();
    for (int st = 128; st > 0; st >>= 1) {
      if (tid < st) sm.t.rv[tid] = fmaxf(sm.t.rv[tid], sm.t.rv[tid + st]);
      __syncthreads();
    }
    float zmax = sm.t.rv[0]; __syncthreads();
    float sp = 0.f; float ev[4];
    #pragma unroll
    for (int r = 0; r < 4; r++) { ev[r] = __expf(zv[r] - zmax); sp += ev[r]; }
    sm.t.rv[tid] = sp; __syncthreads();
    for (int st = 128; st > 0; st >>= 1) {
      if (tid < st) sm.t.rv[tid] += sm.t.rv[tid + st];
      __syncthreads();
    }
    float ssum = sm.t.rv[0]; __syncthreads();
    #pragma unroll
    for (int r = 0; r < 4; r++) sm.t.zbuf[r * 256 + tid] = ev[r] / ssum;
    __syncthreads();
    for (int t = 0; t < 4; t++) {
      float bv = -2.0f; int bi = 0;
      #pragma unroll
      for (int r = 0; r < 4; r++) {
        int m = r * 256 + tid;
        float v = sm.t.zbuf[m];
        if (v > bv) { bv = v; bi = m; }
      }
      sm.t.rv[tid] = bv; sm.t.ri[tid] = bi; __syncthreads();
      for (int st = 128; st > 0; st >>= 1) {
        if (tid < st) {
          float v2 = sm.t.rv[tid + st]; int i2 = sm.t.ri[tid + st];
          if (v2 > sm.t.rv[tid] || (v2 == sm.t.rv[tid] && i2 < sm.t.ri[tid])) {
            sm.t.rv[tid] = v2; sm.t.ri[tid] = i2;
          }
        }
        __syncthreads();
      }
      if (tid == 0) { sm.t.chosen[t] = sm.t.ri[0]; sm.t.zbuf[sm.t.ri[0]] = -2.0f; }
      __syncthreads();
    }
    if (tid < 16) {
      int t = tid & 3, g2 = tid >> 2;
      int dh = g2 >> 1, dw = g2 & 1;
      int m = sm.t.chosen[t];
      int hi = (m >> 5) * 2 + dh, wi = (m & 31) * 2 + dw;
      sm.t.pos[g2 * 4 + t] = hi * 64 + wi;
    }
    __syncthreads();
    for (int i = tid; i < 16 * 256; i += 256) {
      int j = i >> 8, c = i & 255;
      sm.t.xg[j][c] = x[((size_t)b * 256 + c) * NSP + sm.t.pos[j]];
    }
    // gemv via LDS-staged W (four 64-c chunks)
    const int dd = tid & 63, jg = tid >> 6;
    const float bia = bkv[h * 64 + dd];
    float a4[4] = {bia, bia, bia, bia};
    for (int cc2 = 0; cc2 < 4; cc2++) {
      __syncthreads();
      for (int i = tid; i < 4096; i += 256) {
        int r = i >> 6, c = i & 63;
        sm.t.wl[r][c] = Wkv[(size_t)(h * 64 + r) * 256 + cc2 * 64 + c];
      }
      __syncthreads();
      #pragma unroll
      for (int jj = 0; jj < 4; jj++) {
        int j = jg * 4 + jj;
        float a = 0.f;
        #pragma unroll 8
        for (int c = 0; c < 64; c++) a += sm.t.xg[j][cc2 * 64 + c] * sm.t.wl[dd][c];
        a4[jj] += a;
      }
    }
    #pragma unroll
    for (int jj = 0; jj < 4; jj++) {
      int j = jg * 4 + jj;
      if (dd < 32) {
        g_tkKbf[((size_t)bh * 16 + j) * 32 + dd] = f2bf(a4[jj]);
      } else {
        int d = dd - 32;
        g_tkVT[((size_t)bh * 32 + d) * 32 + j] = f2bf(a4[jj]);
        g_tkVT[((size_t)bh * 32 + d) * 32 + 16 + j] = 0;
      }
    }
  } else {
    // ================= vpe =================
    const int idx = blockIdx.x - 16;
    const int c = idx & 255, b = idx >> 8;
    const int h = c >> 5, d = c & 31;
    const float* vrow = g_kv + ((size_t)b * 512 + h * 64 + 32 + d) * NUSP;
    for (int i = tid; i < 1024; i += 256) sm.v.src[i >> 5][i & 31] = vrow[i];
    if (tid < 49) sm.v.wk[tid] = Wpe[c * 49 + tid];
    __syncthreads();
    const float bia = bpe[c];
    for (int i = tid; i < 1024; i += 256) {
      int hu = i >> 5, wu = i & 31;
      float s = bia;
      #pragma unroll
      for (int kh = 0; kh < 7; kh++) {
        int ih = hu + kh - 3;
        if (ih < 0 || ih > 31) continue;
        #pragma unroll
        for (int kw = 0; kw < 7; kw++) {
          int iw = wu + kw - 3;
          if (iw < 0 || iw > 31) continue;
          s += sm.v.src[ih][iw] * sm.v.wk[kh * 7 + kw];
        }
      }
      sm.v.pl[hu][wu] = s;
    }
    __syncthreads();
    float* orow = g_vpe + ((size_t)b * 256 + c) * NSP;
    for (int i = tid; i < 4096; i += 256) {
      int hh = i >> 6, ww = i & 63;
      int ih = hh >> 1, iw = ww >> 1;
      int ih2 = (hh & 1) ? min(ih + 1, 31) : max(ih - 1, 0);
      int iw2 = (ww & 1) ? min(iw + 1, 31) : max(iw - 1, 0);
      float a  = 0.75f * sm.v.pl[ih][iw]  + 0.25f * sm.v.pl[ih][iw2];
      float bb = 0.75f * sm.v.pl[ih2][iw] + 0.25f * sm.v.pl[ih2][iw2];
      orow[i] = 0.75f * a + 0.25f * bb;
    }
  }
}

// ---------- MFMA flash v8: 2 q-tiles per wave (ILP + shared K/V frags) ----------
// grid (32, 16), 4 waves; wave w owns q-rows n0 = bx*128 + w*32 (two 16-q tiles).
// Independent waves, per-wave fused epilogue, exp2 softmax (qbf pre-scaled).
__global__ __launch_bounds__(256) void k_flash(const float* __restrict__ bg) {
  const int bh = blockIdx.y;
  const int b = bh >> 3, h = bh & 7;
  const int tid = threadIdx.x;
  const int lane = tid & 63;
  const int w = tid >> 6;
  const int col = lane & 15;
  const int quad = lane >> 4;
  const int n0 = blockIdx.x * 128 + w * 32;

  __shared__ short Ps[8][16][88];
  short* PsA = &Ps[w * 2][0][0];
  short* PsB = &Ps[w * 2 + 1][0][0];

  const short* kb = g_kbf + (size_t)bh * NUSP * 32;
  const short* vb = g_vbf + (size_t)bh * 32 * NUSP;

  short8 qfA = *(const short8*)&g_qbf[((size_t)bh * NSP + n0 + col) * 32 + quad * 8];
  short8 qfB = *(const short8*)&g_qbf[((size_t)bh * NSP + n0 + 16 + col) * 32 + quad * 8];

  f32x4 oA0 = {0,0,0,0}, oA1 = {0,0,0,0}, oB0 = {0,0,0,0}, oB1 = {0,0,0,0};
  float lA[4] = {0,0,0,0}, lB[4] = {0,0,0,0};

  for (int kt = 0; kt < 16; kt++) {
    short8 kf[4];
    #pragma unroll
    for (int t = 0; t < 4; t++)
      kf[t] = *(const short8*)&kb[((size_t)(kt * 64 + t * 16 + col)) * 32 + quad * 8];
    f32x4 sA[4], sB[4];
    #pragma unroll
    for (int t = 0; t < 4; t++) {
      f32x4 z = {0,0,0,0};
      sA[t] = __builtin_amdgcn_mfma_f32_16x16x32_bf16(qfA, kf[t], z, 0, 0, 0);
      sB[t] = __builtin_amdgcn_mfma_f32_16x16x32_bf16(qfB, kf[t], z, 0, 0, 0);
    }
    #pragma unroll
    for (int t = 0; t < 4; t++)
      #pragma unroll
      for (int r = 0; r < 4; r++) {
        float pA = fexp2(sA[t][r]);
        float pB = fexp2(sB[t][r]);
        sA[t][r] = pA; lA[r] += pA;
        sB[t][r] = pB; lB[r] += pB;
      }
    #pragma unroll
    for (int t = 0; t < 4; t++)
      #pragma unroll
      for (int r = 0; r < 4; r++) {
        PsA[(quad * 4 + r) * 88 + t * 16 + col] = f2bf(sA[t][r]);
        PsB[(quad * 4 + r) * 88 + t * 16 + col] = f2bf(sB[t][r]);
      }
    short8 vf0 = *(const short8*)&vb[(size_t)col * NUSP + kt * 64 + quad * 8];
    short8 vf1 = *(const short8*)&vb[(size_t)(col + 16) * NUSP + kt * 64 + quad * 8];
    short8 vf2 = *(const short8*)&vb[(size_t)col * NUSP + kt * 64 + 32 + quad * 8];
    short8 vf3 = *(const short8*)&vb[(size_t)(col + 16) * NUSP + kt * 64 + 32 + quad * 8];
    short8 pA0 = *(const short8*)&PsA[col * 88 + quad * 8];
    short8 pA1 = *(const short8*)&PsA[col * 88 + 32 + quad * 8];
    short8 pB0 = *(const short8*)&PsB[col * 88 + quad * 8];
    short8 pB1 = *(const short8*)&PsB[col * 88 + 32 + quad * 8];
    oA0 = __builtin_amdgcn_mfma_f32_16x16x32_bf16(pA0, vf0, oA0, 0, 0, 0);
    oB0 = __builtin_amdgcn_mfma_f32_16x16x32_bf16(pB0, vf0, oB0, 0, 0, 0);
    oA1 = __builtin_amdgcn_mfma_f32_16x16x32_bf16(pA0, vf1, oA1, 0, 0, 0);
    oB1 = __builtin_amdgcn_mfma_f32_16x16x32_bf16(pB0, vf1, oB1, 0, 0, 0);
    oA0 = __builtin_amdgcn_mfma_f32_16x16x32_bf16(pA1, vf2, oA0, 0, 0, 0);
    oB0 = __builtin_amdgcn_mfma_f32_16x16x32_bf16(pB1, vf2, oB0, 0, 0, 0);
    oA1 = __builtin_amdgcn_mfma_f32_16x16x32_bf16(pA1, vf3, oA1, 0, 0, 0);
    oB1 = __builtin_amdgcn_mfma_f32_16x16x32_bf16(pB1, vf3, oB1, 0, 0, 0);
  }
  // l reductions over the 16-col group
  #pragma unroll
  for (int st = 1; st < 16; st <<= 1)
    #pragma unroll
    for (int r = 0; r < 4; r++) {
      lA[r] += __shfl_xor(lA[r], st, 64);
      lB[r] += __shfl_xor(lB[r], st, 64);
    }

  // ===== per-wave epilogue, per tile =====
  const float bg0 = bg[col], bg1 = bg[col + 16];
  short8 kff = *(const short8*)&g_tkKbf[(size_t)bh * 512 + col * 32 + quad * 8];
  short8 vt0 = *(const short8*)&g_tkVT[(size_t)bh * 1024 + col * 32 + quad * 8];
  short8 vt1 = *(const short8*)&g_tkVT[(size_t)bh * 1024 + (col + 16) * 32 + quad * 8];
  short8 b1a = *(const short8*)&g_wgbf[col * 64 + quad * 8];
  short8 b1b = *(const short8*)&g_wgbf[col * 64 + 32 + quad * 8];
  short8 b2a = *(const short8*)&g_wgbf[(col + 16) * 64 + quad * 8];
  short8 b2b = *(const short8*)&g_wgbf[(col + 16) * 64 + 32 + quad * 8];

  #pragma unroll
  for (int tt = 0; tt < 2; tt++) {
    const int nt = n0 + tt * 16;
    short8 qf = tt ? qfB : qfA;
    f32x4 o0 = tt ? oB0 : oA0;
    f32x4 o1 = tt ? oB1 : oA1;
    float* lr = tt ? lB : lA;
    short* myPs = tt ? PsB : PsA;
    f32x4 zf = {0,0,0,0};
    f32x4 co0, co1;
    #pragma unroll
    for (int r = 0; r < 4; r++) {
      float inv = 1.0f / lr[r];
      co0[r] = o0[r] * inv;
      co1[r] = o1[r] * inv;
    }
    // fine scores
    f32x4 sf = __builtin_amdgcn_mfma_f32_16x16x32_bf16(qf, kff, zf, 0, 0, 0);
    float fl[4];
    #pragma unroll
    for (int r = 0; r < 4; r++) { float p = fexp2(sf[r]); sf[r] = p; fl[r] = p; }
    #pragma unroll
    for (int st = 1; st < 16; st <<= 1)
      #pragma unroll
      for (int r = 0; r < 4; r++) fl[r] += __shfl_xor(fl[r], st, 64);
    #pragma unroll
    for (int r = 0; r < 4; r++)
      myPs[(quad * 4 + r) * 88 + col] = f2bf(sf[r]);
    short8 pff = {0, 0, 0, 0, 0, 0, 0, 0};
    if (quad < 2) pff = *(const short8*)&myPs[col * 88 + quad * 8];
    f32x4 rf0 = __builtin_amdgcn_mfma_f32_16x16x32_bf16(pff, vt0, zf, 0, 0, 0);
    f32x4 rf1 = __builtin_amdgcn_mfma_f32_16x16x32_bf16(pff, vt1, zf, 0, 0, 0);
    #pragma unroll
    for (int r = 0; r < 4; r++) {
      float inv = 1.0f / fl[r];
      rf0[r] *= inv; rf1[r] *= inv;
    }
    // fusion tile [q][64]
    #pragma unroll
    for (int r = 0; r < 4; r++) {
      int q = quad * 4 + r;
      myPs[q * 88 + col]      = f2bf(co0[r]);
      myPs[q * 88 + col + 16] = f2bf(co1[r]);
      myPs[q * 88 + col + 32] = f2bf(rf0[r]);
      myPs[q * 88 + col + 48] = f2bf(rf1[r]);
    }
    short8 a1 = *(const short8*)&myPs[col * 88 + quad * 8];
    short8 a2 = *(const short8*)&myPs[col * 88 + 32 + quad * 8];
    f32x4 G0 = __builtin_amdgcn_mfma_f32_16x16x32_bf16(a1, b1a, zf, 0, 0, 0);
    G0 = __builtin_amdgcn_mfma_f32_16x16x32_bf16(a2, b1b, G0, 0, 0, 0);
    f32x4 G1 = __builtin_amdgcn_mfma_f32_16x16x32_bf16(a1, b2a, zf, 0, 0, 0);
    G1 = __builtin_amdgcn_mfma_f32_16x16x32_bf16(a2, b2b, G1, 0, 0, 0);
    const float* vpe0 = g_vpe + ((size_t)(b * 256 + h * 32 + col)) * NSP + nt;
    const float* vpe1 = g_vpe + ((size_t)(b * 256 + h * 32 + col + 16)) * NSP + nt;
    short* dstb = g_sumT + ((size_t)b * NSP + nt) * 256 + h * 32;
    #pragma unroll
    for (int r = 0; r < 4; r++) {
      int q = quad * 4 + r;
      float g0 = 1.0f / (1.0f + __expf(-(G0[r] + bg0)));
      float g1 = 1.0f / (1.0f + __expf(-(G1[r] + bg1)));
      float out0 = g0 * rf0[r] + (1.0f - g0) * co0[r] + vpe0[q];
      float out1 = g1 * rf1[r] + (1.0f - g1) * co1[r] + vpe1[q];
      dstb[(size_t)q * 256 + col]      = f2bf(out0);
      dstb[(size_t)q * 256 + col + 16] = f2bf(out1);
    }
  }
}

// ---------- k_gemm_proj: final projection, f32 out ----------
__global__ __launch_bounds__(256) void k_gemm_proj(const float* __restrict__ bias,
                                                   float* __restrict__ out) {
  const int b = blockIdx.z;
  const int o0 = blockIdx.y * 64;
  const int n0 = blockIdx.x * 64;
  const int tid = threadIdx.x;
  const int lane = tid & 63, w = tid >> 6, col = lane & 15, quad = lane >> 4;
  f32x4 acc[4] = {{0,0,0,0},{0,0,0,0},{0,0,0,0},{0,0,0,0}};
  gemm_mfma(g_wbf + 196608, g_sumT, b, o0, n0, NSP, w, col, quad, acc);
  #pragma unroll
  for (int r = 0; r < 4; r++) {
    int o = o0 + w * 16 + quad * 4 + r;
    float bv = bias[o];
    float* orow = out + ((size_t)b * 256 + o) * NSP + n0;
    #pragma unroll
    for (int t = 0; t < 4; t++)
      orow[t * 16 + col] = acc[t][r] + bv;
  }
}

extern "C" void kernel_launch(void* const* d_in, const int* in_sizes, int n_in,
                              void* d_out, int out_size, void* d_ws, size_t ws_size,
                              hipStream_t stream) {
  const float* x     = (const float*)d_in[0];
  const float* upper = (const float*)d_in[1];
  const float* Wq    = (const float*)d_in[2];
  const float* bq    = (const float*)d_in[3];
  const float* Wkv   = (const float*)d_in[4];
  const float* bkv   = (const float*)d_in[5];
  const float* Wproj = (const float*)d_in[6];
  const float* bproj = (const float*)d_in[7];
  const float* Wpe   = (const float*)d_in[8];
  const float* bpe   = (const float*)d_in[9];
  const float* Wg    = (const float*)d_in[10];
  const float* bg    = (const float*)d_in[11];
  float* out = (float*)d_out;
  (void)d_ws; (void)ws_size; (void)in_sizes; (void)n_in; (void)out_size;

  k_pack_in<<<dim3(192), dim3(256), 0, stream>>>(x, upper, Wq, Wkv, Wproj, Wg);
  k_gemms<<<dim3(768), dim3(256), 0, stream>>>(bq, bkv);
  k_mid<<<dim3(528), dim3(256), 0, stream>>>(x, Wkv, bkv, Wpe, bpe);
  k_flash<<<dim3(32, 16), dim3(256), 0, stream>>>(bg);
  k_gemm_proj<<<dim3(64, 4, 2), dim3(256), 0, stream>>>(bproj, out);
}